// Round 2
// baseline (23130.502 us; speedup 1.0000x reference)
//
#include <hip/hip_runtime.h>
#include <hip/hip_bf16.h>

// Seq2Seq (batch=1): enc LSTM (S=256) -> dec LSTM (T=256) -> linear (32000)
// -> log_softmax.
// v2: the 512-step recurrence runs in ONE persistent kernel (256 blocks,
// 1/CU, all co-resident). Whh_enc + Whh_dec live entirely in registers
// (64 f32 each per thread = 128 VGPRs); h is exchanged through global with
// a device-scope monotonic-counter grid barrier; c stays in registers.

#define HDIM 1024
#define SLEN 256
#define TLEN 256
#define VOUTN 32000
#define G4 4096
#define NBLK 256

typedef __bf16 bf16_t;
typedef __bf16 bf16x8 __attribute__((ext_vector_type(8)));
typedef float f32x4 __attribute__((ext_vector_type(4)));

static __device__ inline bf16x8 cvt8(float4 a, float4 b) {
    bf16x8 r;
    r[0] = (__bf16)a.x; r[1] = (__bf16)a.y; r[2] = (__bf16)a.z; r[3] = (__bf16)a.w;
    r[4] = (__bf16)b.x; r[5] = (__bf16)b.y; r[6] = (__bf16)b.z; r[7] = (__bf16)b.w;
    return r;
}

// ---------------- input GEMM: xw[t][n] = emb[tok(t)].Wih[n] + bih[n] + bhh[n]
__global__ __launch_bounds__(256) void input_gemm(
    const float* __restrict__ emb, const int* __restrict__ toks,
    const int* __restrict__ start, const float* __restrict__ W,
    const float* __restrict__ bih, const float* __restrict__ bhh,
    float* __restrict__ out)
{
    __shared__ int stok[SLEN];
    int tid = threadIdx.x;
    {
        int t = tid, tok;
        if (start) tok = (t == 0) ? start[0] : toks[t - 1];
        else       tok = toks[t];
        stok[t] = tok;
    }
    __syncthreads();

    int wave = tid >> 6, lane = tid & 63;
    int l15 = lane & 15, quad = lane >> 4;
    int n = (blockIdx.x * 4 + wave) * 16 + l15;
    const float* wrow = W + (size_t)n * HDIM + quad * 8;

    f32x4 acc[16] = {};
    for (int kt = 0; kt < HDIM / 32; ++kt) {
        float4 b0 = *(const float4*)(wrow + kt * 32);
        float4 b1 = *(const float4*)(wrow + kt * 32 + 4);
        bf16x8 bf = cvt8(b0, b1);
#pragma unroll
        for (int mt = 0; mt < 16; ++mt) {
            const float* arow = emb + (size_t)stok[mt * 16 + l15] * HDIM + kt * 32 + quad * 8;
            bf16x8 af = cvt8(*(const float4*)arow, *(const float4*)(arow + 4));
            acc[mt] = __builtin_amdgcn_mfma_f32_16x16x32_bf16(af, bf, acc[mt], 0, 0, 0);
        }
    }
    float bias = bih[n] + bhh[n];
#pragma unroll
    for (int mt = 0; mt < 16; ++mt)
#pragma unroll
        for (int r = 0; r < 4; ++r)
            out[(size_t)(mt * 16 + quad * 4 + r) * G4 + n] = acc[mt][r] + bias;
}

// ---------------- persistent recurrence -------------------------------------
// Block b owns hidden units j0=4b..4b+3 (rows {g*1024+j}, g=0..3).
// tid = grp*16 + klane; grp = g*4 + jl selects row; klane covers K.
// Thread's K-slice (interleaved float4s): indices klane + 16*i, i=0..15.
__global__ __launch_bounds__(256, 1) void lstm_persist(
    const float* __restrict__ encW,   // enc_Whh [4096,1024]
    const float* __restrict__ decW,   // dec_Whh [4096,1024]
    const float* __restrict__ encXW,  // [256,4096]
    const float* __restrict__ decXW,  // [256,4096]
    float* __restrict__ hglob,        // [1024] f32 (zeroed)
    bf16_t* __restrict__ Hs,          // [256,1024] bf16 out
    int* __restrict__ cnt)            // barrier counter (zeroed)
{
    __shared__ float sh[HDIM];
    __shared__ float sg[16];
    int tid = threadIdx.x;
    int grp = tid >> 4, klane = tid & 15;
    int g = grp >> 2, jl = grp & 3;
    int j0 = blockIdx.x * 4;
    int row = g * HDIM + j0 + jl;

    // load weight slices into registers (read-once, coalesced per 16-lane run)
    const float4* eW4 = (const float4*)(encW + (size_t)row * HDIM);
    const float4* dW4 = (const float4*)(decW + (size_t)row * HDIM);
    float4 we[16], wd[16];
#pragma unroll
    for (int i = 0; i < 16; ++i) we[i] = eW4[klane + 16 * i];
#pragma unroll
    for (int i = 0; i < 16; ++i) wd[i] = dW4[klane + 16 * i];

    float cval = 0.f;                 // tid<4: c for unit j0+tid
    const float4* hg4 = (const float4*)hglob;

    for (int t = 0; t < SLEN + TLEN; ++t) {
        // stage h into LDS
        ((float4*)sh)[tid] = hg4[tid];
        __syncthreads();

        const float4* sh4 = (const float4*)sh;
        float sum = 0.f;
        if (t < SLEN) {
#pragma unroll
            for (int i = 0; i < 16; ++i) {
                float4 w = we[i], h = sh4[klane + 16 * i];
                sum += w.x * h.x + w.y * h.y + w.z * h.z + w.w * h.w;
            }
        } else {
#pragma unroll
            for (int i = 0; i < 16; ++i) {
                float4 w = wd[i], h = sh4[klane + 16 * i];
                sum += w.x * h.x + w.y * h.y + w.z * h.z + w.w * h.w;
            }
        }
        sum += __shfl_down(sum, 8, 16);
        sum += __shfl_down(sum, 4, 16);
        sum += __shfl_down(sum, 2, 16);
        sum += __shfl_down(sum, 1, 16);
        if (klane == 0) sg[grp] = sum;
        __syncthreads();

        if (tid < 4) {
            int j = j0 + tid;
            const float* xwt = (t < SLEN) ? (encXW + (size_t)t * G4)
                                          : (decXW + (size_t)(t - SLEN) * G4);
            float gi = sg[0 + tid]  + xwt[0 * HDIM + j];
            float gf = sg[4 + tid]  + xwt[1 * HDIM + j];
            float gg = sg[8 + tid]  + xwt[2 * HDIM + j];
            float go = sg[12 + tid] + xwt[3 * HDIM + j];
            float ii = 1.f / (1.f + expf(-gi));
            float ff = 1.f / (1.f + expf(-gf));
            float gv = tanhf(gg);
            float oo = 1.f / (1.f + expf(-go));
            cval = ff * cval + ii * gv;
            float hn = oo * tanhf(cval);
            hglob[j] = hn;
            if (t >= SLEN) Hs[(size_t)(t - SLEN) * HDIM + j] = (bf16_t)hn;
        }

        // grid barrier: release h, arrive, spin, acquire
        __threadfence();
        __syncthreads();
        if (tid == 0) {
            __hip_atomic_fetch_add(cnt, 1, __ATOMIC_ACQ_REL, __HIP_MEMORY_SCOPE_AGENT);
            int target = NBLK * (t + 1);
            while (__hip_atomic_load(cnt, __ATOMIC_ACQUIRE, __HIP_MEMORY_SCOPE_AGENT) < target)
                __builtin_amdgcn_s_sleep(1);
        }
        __syncthreads();
        __threadfence();
    }
}

// ---------------- output GEMM: logits = Hs @ lin_W^T + b ---------------------
__global__ __launch_bounds__(256) void out_gemm(
    const bf16_t* __restrict__ Hs, const float* __restrict__ W,
    const float* __restrict__ bias, float* __restrict__ out)
{
    int tid = threadIdx.x;
    int wave = tid >> 6, lane = tid & 63;
    int l15 = lane & 15, quad = lane >> 4;
    int n = (blockIdx.x * 4 + wave) * 16 + l15;
    const float* wrow = W + (size_t)n * HDIM + quad * 8;

    f32x4 acc[16] = {};
    for (int kt = 0; kt < HDIM / 32; ++kt) {
        float4 b0 = *(const float4*)(wrow + kt * 32);
        float4 b1 = *(const float4*)(wrow + kt * 32 + 4);
        bf16x8 bf = cvt8(b0, b1);
#pragma unroll
        for (int mt = 0; mt < 16; ++mt) {
            bf16x8 af = *(const bf16x8*)(Hs + (size_t)(mt * 16 + l15) * HDIM + kt * 32 + quad * 8);
            acc[mt] = __builtin_amdgcn_mfma_f32_16x16x32_bf16(af, bf, acc[mt], 0, 0, 0);
        }
    }
    float bv = bias[n];
#pragma unroll
    for (int mt = 0; mt < 16; ++mt)
#pragma unroll
        for (int r = 0; r < 4; ++r)
            out[(size_t)(mt * 16 + quad * 4 + r) * VOUTN + n] = acc[mt][r] + bv;
}

// ---------------- log_softmax per row ---------------------------------------
__global__ __launch_bounds__(256) void log_softmax_k(float* __restrict__ out)
{
    float* row = out + (size_t)blockIdx.x * VOUTN;
    int tid = threadIdx.x;
    int wave = tid >> 6, lane = tid & 63;
    __shared__ float sm[4], ss[4];

    float m = -1e30f;
    for (int i = tid; i < VOUTN; i += 256) m = fmaxf(m, row[i]);
    for (int o = 32; o; o >>= 1) m = fmaxf(m, __shfl_down(m, o, 64));
    if (lane == 0) sm[wave] = m;
    __syncthreads();
    float bm = fmaxf(fmaxf(sm[0], sm[1]), fmaxf(sm[2], sm[3]));

    float s = 0.f;
    for (int i = tid; i < VOUTN; i += 256) s += expf(row[i] - bm);
    for (int o = 32; o; o >>= 1) s += __shfl_down(s, o, 64);
    if (lane == 0) ss[wave] = s;
    __syncthreads();
    float lse = bm + logf(ss[0] + ss[1] + ss[2] + ss[3]);

    for (int i = tid; i < VOUTN; i += 256) row[i] -= lse;
}

extern "C" void kernel_launch(void* const* d_in, const int* in_sizes, int n_in,
                              void* d_out, int out_size, void* d_ws, size_t ws_size,
                              hipStream_t stream) {
    const int*   src     = (const int*)d_in[0];
    const int*   trg     = (const int*)d_in[1];
    const int*   start   = (const int*)d_in[2];
    const float* enc_emb = (const float*)d_in[3];
    const float* enc_Wih = (const float*)d_in[4];
    const float* enc_Whh = (const float*)d_in[5];
    const float* enc_bih = (const float*)d_in[6];
    const float* enc_bhh = (const float*)d_in[7];
    const float* dec_emb = (const float*)d_in[8];
    const float* dec_Wih = (const float*)d_in[9];
    const float* dec_Whh = (const float*)d_in[10];
    const float* dec_bih = (const float*)d_in[11];
    const float* dec_bhh = (const float*)d_in[12];
    const float* lin_W   = (const float*)d_in[13];
    const float* lin_b   = (const float*)d_in[14];
    float* out = (float*)d_out;

    char* ws = (char*)d_ws;
    float*  encXW = (float*)(ws);                 // 4 MiB
    float*  decXW = (float*)(ws + 4194304);       // 4 MiB
    bf16_t* Hs    = (bf16_t*)(ws + 8388608);      // 512 KiB
    float*  hglob = (float*)(ws + 8912896);       // 4 KiB
    int*    cnt   = (int*)(ws + 8916992);         // barrier counter

    // zero h0 + barrier counter (ws is re-poisoned 0xAA before every launch,
    // so this also re-arms the barrier for each graph replay)
    hipMemsetAsync(hglob, 0, HDIM * sizeof(float) + 128, stream);

    input_gemm<<<64, 256, 0, stream>>>(enc_emb, src, nullptr, enc_Wih, enc_bih, enc_bhh, encXW);
    input_gemm<<<64, 256, 0, stream>>>(dec_emb, trg, start,   dec_Wih, dec_bih, dec_bhh, decXW);

    lstm_persist<<<NBLK, 256, 0, stream>>>(enc_Whh, dec_Whh, encXW, decXW, hglob, Hs, cnt);

    out_gemm<<<500, 256, 0, stream>>>(Hs, lin_W, lin_b, out);
    log_softmax_k<<<256, 256, 0, stream>>>(out);
}